// Round 1
// baseline (184.868 us; speedup 1.0000x reference)
//
#include <hip/hip_runtime.h>
#include <hip/hip_bf16.h>

typedef __attribute__((ext_vector_type(8))) short bf16x8;
typedef __attribute__((ext_vector_type(4))) float f32x4;
typedef __attribute__((ext_vector_type(4))) unsigned short u16x4;

#define NEGINF (-3.4028234663852886e38f)

__device__ __forceinline__ unsigned short f2b(float f) {
    union { float f; unsigned u; } x; x.f = f;
    unsigned r = x.u + 0x7FFFu + ((x.u >> 16) & 1u);
    return (unsigned short)(r >> 16);
}
__device__ __forceinline__ float b2f(unsigned short b) {
    union { unsigned u; float f; } x; x.u = ((unsigned)b) << 16;
    return x.f;
}

// ---------------- scan: per-row '@' span, CITSEG pos ----------------
__global__ __launch_bounds__(64) void scan_k(const int* __restrict__ tokens,
                                             int* __restrict__ meta) {
    const int S = 512, BIG = 1 << 20;
    int b = blockIdx.x, l = threadIdx.x;
    const int* row = tokens + (size_t)b * S;
    int base = l * 8;
    int toks[8];
#pragma unroll
    for (int i = 0; i < 8; ++i) toks[i] = row[base + i];
    int am = 0, cnt = 0, minAt = BIG, minC = BIG;
#pragma unroll
    for (int i = 0; i < 8; ++i) {
        if (toks[i] == 5) { am |= 1 << i; cnt++; if (base + i < minAt) minAt = base + i; }
        if (toks[i] == 7) { if (base + i < minC) minC = base + i; }
    }
    for (int off = 1; off < 64; off <<= 1) {
        minAt = min(minAt, __shfl_xor(minAt, off));
        minC  = min(minC,  __shfl_xor(minC,  off));
        cnt  += __shfl_xor(cnt, off);
    }
    int first = minAt;
    int minAt2 = BIG;
#pragma unroll
    for (int i = 0; i < 8; ++i)
        if ((am >> i) & 1) { int idx = base + i; if (idx > first && idx < minAt2) minAt2 = idx; }
    for (int off = 1; off < 64; off <<= 1) minAt2 = min(minAt2, __shfl_xor(minAt2, off));
    if (l == 0) {
        int ge2 = (cnt >= 2) ? 1 : 0;
        int start = ge2 ? first : 0;
        int end = ge2 ? minAt2 : S;
        int anyKeep = (ge2 && (start > 0 || end < S - 1)) ? 1 : 0;
        int has_c = (minC < S) ? 1 : 0;
        int cpos = min(minC, S - 1);
        int* m = meta + b * 6;
        m[0] = start; m[1] = end; m[2] = cpos; m[3] = has_c; m[4] = anyKeep; m[5] = 0;
    }
}

// ---------------- masked max pool: partials over 8 s-chunks ----------------
__global__ __launch_bounds__(192) void pool_k(const float* __restrict__ hs,
                                              const int* __restrict__ meta,
                                              float* __restrict__ part) {
    int b = blockIdx.x >> 3, ch = blockIdx.x & 7;
    int start = meta[b * 6 + 0], end = meta[b * 6 + 1];
    int t = threadIdx.x;
    f32x4 m = { NEGINF, NEGINF, NEGINF, NEGINF };
    const float* basep = hs + (size_t)b * 512 * 768 + t * 4;
    int s0 = ch * 64;
#pragma unroll 4
    for (int s = s0; s < s0 + 64; ++s) {
        if (s >= start && s <= end) continue;
        f32x4 v = *(const f32x4*)(basep + (size_t)s * 768);
#pragma unroll
        for (int j = 0; j < 4; ++j) m[j] = fmaxf(m[j], v[j]);
    }
    *(f32x4*)(part + ((size_t)b * 8 + ch) * 768 + t * 4) = m;
}

// ---------------- pack: reduce partials -> xA[:,0:768] bf16; gather CITSEG row ----------------
__global__ __launch_bounds__(192) void pack_k(const float* __restrict__ hs,
                                              const float* __restrict__ part,
                                              const int* __restrict__ meta,
                                              unsigned short* __restrict__ xA,
                                              unsigned short* __restrict__ citA) {
    int b = blockIdx.x, t = threadIdx.x;
    const float* p = part + (size_t)b * 8 * 768 + t * 4;
    f32x4 m = *(const f32x4*)p;
#pragma unroll
    for (int ch = 1; ch < 8; ++ch) {
        f32x4 v = *(const f32x4*)(p + (size_t)ch * 768);
#pragma unroll
        for (int j = 0; j < 4; ++j) m[j] = fmaxf(m[j], v[j]);
    }
    if (!meta[b * 6 + 4]) {
        f32x4 z = {0.f, 0.f, 0.f, 0.f};
        m = z;
    }
    u16x4 o;
#pragma unroll
    for (int j = 0; j < 4; ++j) o[j] = f2b(m[j]);
    *(u16x4*)(xA + (size_t)b * 1536 + t * 4) = o;

    int cpos = meta[b * 6 + 2];
    f32x4 c = *(const f32x4*)(hs + ((size_t)b * 512 + cpos) * 768 + t * 4);
    u16x4 co;
#pragma unroll
    for (int j = 0; j < 4; ++j) co[j] = f2b(c[j]);
    *(u16x4*)(citA + (size_t)b * 768 + t * 4) = co;
}

// ---------------- transpose + f32->bf16: out[n][k] = in[k][n], zero-padded ----------------
__global__ __launch_bounds__(256) void trans_k(const float* __restrict__ in, int K, int N,
                                               unsigned short* __restrict__ out, int ldo) {
    __shared__ float tile[32][33];
    int n0 = blockIdx.x * 32, k0 = blockIdx.y * 32;
    int tx = threadIdx.x, ty = threadIdx.y;
#pragma unroll
    for (int i = 0; i < 4; ++i) {
        int k = k0 + ty * 4 + i, n = n0 + tx;
        tile[ty * 4 + i][tx] = (k < K && n < N) ? in[(size_t)k * N + n] : 0.f;
    }
    __syncthreads();
#pragma unroll
    for (int i = 0; i < 4; ++i) {
        int n = n0 + ty * 4 + i, k = k0 + tx;
        out[(size_t)n * ldo + k] = f2b(tile[tx][ty * 4 + i]);
    }
}

// ---------------- bf16 MFMA GEMM: C[M][N] = A[M][K] * Bt[N][K]^T, fused epilogue ----------------
// EPI: 0 = (+bias)*has_c  1 = +bias  2 = relu(+bias)
template<int EPI>
__global__ __launch_bounds__(256) void gemm_k(
    const unsigned short* __restrict__ A, int lda,
    const unsigned short* __restrict__ Bt, int ldb,
    const float* __restrict__ bias, const int* __restrict__ meta,
    unsigned short* __restrict__ X, int ldx, int Nreal, int Kp) {
    __shared__ unsigned short As[64 * 64];
    __shared__ unsigned short Bs[64 * 64];
    const int tid = threadIdx.x;
    const int wid = tid >> 6, lane = tid & 63;
    const int m0 = blockIdx.y * 64, n0 = blockIdx.x * 64;
    const int wr = wid >> 1, wc = wid & 1;
    f32x4 acc[2][2];
    const f32x4 zero = {0.f, 0.f, 0.f, 0.f};
#pragma unroll
    for (int mi = 0; mi < 2; ++mi)
#pragma unroll
        for (int nj = 0; nj < 2; ++nj) acc[mi][nj] = zero;

    const int rl = lane >> 3;   // 0..7
    const int c8 = lane & 7;    // 0..7 (16B chunk within 64-elem row)

    for (int kt = 0; kt < Kp; kt += 64) {
        bf16x8 va[2], vb[2];
#pragma unroll
        for (int p = 0; p < 2; ++p) {
            int row = p * 32 + wid * 8 + rl;
            va[p] = *(const bf16x8*)(A + (size_t)(m0 + row) * lda + kt + c8 * 8);
            vb[p] = *(const bf16x8*)(Bt + (size_t)(n0 + row) * ldb + kt + c8 * 8);
        }
        __syncthreads();  // previous tile fully consumed
#pragma unroll
        for (int p = 0; p < 2; ++p) {
            int row = p * 32 + wid * 8 + rl;
            int dst = row * 64 + ((c8 ^ (row & 7)) * 8);   // XOR swizzle
            *(bf16x8*)(As + dst) = va[p];
            *(bf16x8*)(Bs + dst) = vb[p];
        }
        __syncthreads();  // tile ready
#pragma unroll
        for (int kk = 0; kk < 2; ++kk) {
            int k8 = kk * 4 + (lane >> 4);
            bf16x8 af[2], bfr[2];
#pragma unroll
            for (int mi = 0; mi < 2; ++mi) {
                int row = wr * 32 + mi * 16 + (lane & 15);
                af[mi] = *(const bf16x8*)(As + row * 64 + ((k8 ^ (row & 7)) * 8));
            }
#pragma unroll
            for (int nj = 0; nj < 2; ++nj) {
                int row = wc * 32 + nj * 16 + (lane & 15);
                bfr[nj] = *(const bf16x8*)(Bs + row * 64 + ((k8 ^ (row & 7)) * 8));
            }
#pragma unroll
            for (int mi = 0; mi < 2; ++mi)
#pragma unroll
                for (int nj = 0; nj < 2; ++nj)
                    acc[mi][nj] = __builtin_amdgcn_mfma_f32_16x16x32_bf16(
                        af[mi], bfr[nj], acc[mi][nj], 0, 0, 0);
        }
    }
    // epilogue: verified C/D layout col=lane&15, row=(lane>>4)*4+i
#pragma unroll
    for (int mi = 0; mi < 2; ++mi) {
        int rowb = m0 + wr * 32 + mi * 16 + (lane >> 4) * 4;
#pragma unroll
        for (int nj = 0; nj < 2; ++nj) {
            int col = n0 + wc * 32 + nj * 16 + (lane & 15);
            float bv = (col < Nreal) ? bias[col] : 0.f;
#pragma unroll
            for (int i = 0; i < 4; ++i) {
                int row = rowb + i;
                float v = acc[mi][nj][i] + bv;
                if (EPI == 0) v *= (meta[row * 6 + 3] ? 1.f : 0.f);
                if (EPI == 2) v = fmaxf(v, 0.f);
                if (col >= Nreal) v = 0.f;
                X[(size_t)row * ldx + col] = f2b(v);
            }
        }
    }
}

// ---------------- final tiny layer: out[b][j] = x2[b,:] . w3T[j,:] + b3[j] ----------------
__global__ __launch_bounds__(384) void out_k(const unsigned short* __restrict__ x2,
                                             const unsigned short* __restrict__ w3T,
                                             const float* __restrict__ b3,
                                             float* __restrict__ out) {
    int b = blockIdx.x;
    int wid = threadIdx.x >> 6, lane = threadIdx.x & 63;
    const unsigned short* xr = x2 + (size_t)b * 3072;
    const unsigned short* wr = w3T + (size_t)wid * 3072;
    float s = 0.f;
    for (int k0 = lane * 8; k0 < 3072; k0 += 512) {
        bf16x8 xv = *(const bf16x8*)(xr + k0);
        bf16x8 wv = *(const bf16x8*)(wr + k0);
#pragma unroll
        for (int j = 0; j < 8; ++j)
            s += b2f((unsigned short)xv[j]) * b2f((unsigned short)wv[j]);
    }
    for (int off = 1; off < 64; off <<= 1) s += __shfl_xor(s, off);
    if (lane == 0) out[b * 6 + wid] = s + b3[wid];
}

extern "C" void kernel_launch(void* const* d_in, const int* in_sizes, int n_in,
                              void* d_out, int out_size, void* d_ws, size_t ws_size,
                              hipStream_t stream) {
    const int*   tokens = (const int*)d_in[0];
    const float* hs     = (const float*)d_in[1];
    const float* proj_w = (const float*)d_in[2];
    const float* proj_b = (const float*)d_in[3];
    const float* enc_w  = (const float*)d_in[4];
    const float* enc_b  = (const float*)d_in[5];
    const float* w1 = (const float*)d_in[6];
    const float* b1 = (const float*)d_in[7];
    const float* w2 = (const float*)d_in[8];
    const float* b2 = (const float*)d_in[9];
    const float* w3 = (const float*)d_in[10];
    const float* b3 = (const float*)d_in[11];
    float* out = (float*)d_out;

    char* ws = (char*)d_ws;
    size_t off = 0;
    auto alloc = [&](size_t bytes) {
        void* p = ws + off;
        off = (off + bytes + 255) & ~(size_t)255;
        return p;
    };
    int* meta            = (int*)alloc(256 * 6 * sizeof(int));
    float* part          = (float*)alloc((size_t)256 * 8 * 768 * sizeof(float));
    unsigned short* xA   = (unsigned short*)alloc((size_t)256 * 1536 * 2);
    unsigned short* citA = (unsigned short*)alloc((size_t)256 * 768 * 2);
    unsigned short* citB = (unsigned short*)alloc((size_t)256 * 768 * 2);
    unsigned short* x1   = (unsigned short*)alloc((size_t)256 * 3072 * 2);
    unsigned short* x2   = (unsigned short*)alloc((size_t)256 * 3072 * 2);
    unsigned short* projT= (unsigned short*)alloc((size_t)768 * 768 * 2);
    unsigned short* encT = (unsigned short*)alloc((size_t)768 * 768 * 2);
    unsigned short* w1T  = (unsigned short*)alloc((size_t)3072 * 1536 * 2);
    unsigned short* w2T  = (unsigned short*)alloc((size_t)3072 * 3072 * 2);
    unsigned short* w3T  = (unsigned short*)alloc((size_t)32 * 3072 * 2);

    scan_k<<<256, 64, 0, stream>>>(tokens, meta);
    pool_k<<<2048, 192, 0, stream>>>(hs, meta, part);
    pack_k<<<256, 192, 0, stream>>>(hs, part, meta, xA, citA);

    trans_k<<<dim3(24, 24), dim3(32, 8), 0, stream>>>(proj_w, 768, 750, projT, 768);
    trans_k<<<dim3(24, 24), dim3(32, 8), 0, stream>>>(enc_w, 750, 750, encT, 768);
    trans_k<<<dim3(96, 48), dim3(32, 8), 0, stream>>>(w1, 1518, 3036, w1T, 1536);
    trans_k<<<dim3(96, 96), dim3(32, 8), 0, stream>>>(w2, 3036, 3036, w2T, 3072);
    trans_k<<<dim3(1, 96),  dim3(32, 8), 0, stream>>>(w3, 3036, 6, w3T, 3072);

    // G1: cit = (cit_h @ proj_w + proj_b) * has_c     [256x768]x[768x750]
    gemm_k<0><<<dim3(12, 4), 256, 0, stream>>>(citA, 768, projT, 768, proj_b, meta,
                                               citB, 768, 750, 768);
    // G2: cit_enc = cit @ enc_w + enc_b -> xA[:,768:1518]
    gemm_k<1><<<dim3(12, 4), 256, 0, stream>>>(citB, 768, encT, 768, enc_b, meta,
                                               xA + 768, 1536, 750, 768);
    // G3: x1 = relu(xA @ w1 + b1)                      [256x1536]x[1536x3072]
    gemm_k<2><<<dim3(48, 4), 256, 0, stream>>>(xA, 1536, w1T, 1536, b1, meta,
                                               x1, 3072, 3036, 1536);
    // G4: x2 = relu(x1 @ w2 + b2)                      [256x3072]x[3072x3072]
    gemm_k<2><<<dim3(48, 4), 256, 0, stream>>>(x1, 3072, w2T, 3072, b2, meta,
                                               x2, 3072, 3036, 3072);
    // G5: out = x2 @ w3 + b3
    out_k<<<256, 384, 0, stream>>>(x2, w3T, b3, out);
}

// Round 2
// 165.512 us; speedup vs baseline: 1.1169x; 1.1169x over previous
//
#include <hip/hip_runtime.h>
#include <hip/hip_bf16.h>

typedef __attribute__((ext_vector_type(8))) short bf16x8;
typedef __attribute__((ext_vector_type(4))) float f32x4;
typedef __attribute__((ext_vector_type(4))) unsigned short u16x4;

#define NEGINF (-3.4028234663852886e38f)

__device__ __forceinline__ unsigned short f2b(float f) {
    union { float f; unsigned u; } x; x.f = f;
    unsigned r = x.u + 0x7FFFu + ((x.u >> 16) & 1u);
    return (unsigned short)(r >> 16);
}
__device__ __forceinline__ float b2f(unsigned short b) {
    union { unsigned u; float f; } x; x.u = ((unsigned)b) << 16;
    return x.f;
}

__device__ __forceinline__ void load_lds16(const void* g, void* l) {
    __builtin_amdgcn_global_load_lds((const __attribute__((address_space(1))) void*)g,
                                     (__attribute__((address_space(3))) void*)l, 16, 0, 0);
}

// ================= prep: scan (blocks 0..63) + weight transposes =================
__device__ __forceinline__ void trans_tile(const float* __restrict__ in, int K, int N,
                                           unsigned short* __restrict__ out, int ldo,
                                           int bx, int by, int tid, float (*tile)[33]) {
    int n0 = bx * 32, k0 = by * 32;
    int tx = tid & 31, ty = tid >> 5;
#pragma unroll
    for (int i = 0; i < 4; ++i) {
        int k = k0 + ty * 4 + i, n = n0 + tx;
        tile[ty * 4 + i][tx] = (k < K && n < N) ? in[(size_t)k * N + n] : 0.f;
    }
    __syncthreads();
#pragma unroll
    for (int i = 0; i < 4; ++i) {
        int n = n0 + ty * 4 + i, k = k0 + tx;
        out[(size_t)n * ldo + k] = f2b(tile[tx][ty * 4 + i]);
    }
}

__global__ __launch_bounds__(256) void prep_k(
    const int* __restrict__ tokens, int* __restrict__ meta,
    const float* __restrict__ proj_w, const float* __restrict__ enc_w,
    const float* __restrict__ w1, const float* __restrict__ w2,
    unsigned short* __restrict__ projT, unsigned short* __restrict__ encT,
    unsigned short* __restrict__ w1T, unsigned short* __restrict__ w2T) {
    __shared__ float tile[32][33];
    int bid = blockIdx.x, tid = threadIdx.x;
    if (bid < 64) {
        // scan: wave per row
        const int S = 512, BIG = 1 << 20;
        int b = bid * 4 + (tid >> 6), l = tid & 63;
        const int* row = tokens + (size_t)b * S;
        int base = l * 8;
        int toks[8];
#pragma unroll
        for (int i = 0; i < 8; ++i) toks[i] = row[base + i];
        int am = 0, cnt = 0, minAt = BIG, minC = BIG;
#pragma unroll
        for (int i = 0; i < 8; ++i) {
            if (toks[i] == 5) { am |= 1 << i; cnt++; if (base + i < minAt) minAt = base + i; }
            if (toks[i] == 7) { if (base + i < minC) minC = base + i; }
        }
        for (int off = 1; off < 64; off <<= 1) {
            minAt = min(minAt, __shfl_xor(minAt, off));
            minC  = min(minC,  __shfl_xor(minC,  off));
            cnt  += __shfl_xor(cnt, off);
        }
        int first = minAt, minAt2 = BIG;
#pragma unroll
        for (int i = 0; i < 8; ++i)
            if ((am >> i) & 1) { int idx = base + i; if (idx > first && idx < minAt2) minAt2 = idx; }
        for (int off = 1; off < 64; off <<= 1) minAt2 = min(minAt2, __shfl_xor(minAt2, off));
        if (l == 0) {
            int ge2 = (cnt >= 2) ? 1 : 0;
            int start = ge2 ? first : 0;
            int end = ge2 ? minAt2 : S;
            int anyKeep = (ge2 && (start > 0 || end < S - 1)) ? 1 : 0;
            int has_c = (minC < S) ? 1 : 0;
            int cpos = min(minC, S - 1);
            int* m = meta + b * 6;
            m[0] = start; m[1] = end; m[2] = cpos; m[3] = has_c; m[4] = anyKeep; m[5] = 0;
        }
    } else if (bid < 640) {
        int r = bid - 64;   trans_tile(proj_w, 768, 750, projT, 768, r % 24, r / 24, tid, tile);
    } else if (bid < 1216) {
        int r = bid - 640;  trans_tile(enc_w, 750, 750, encT, 768, r % 24, r / 24, tid, tile);
    } else if (bid < 5824) {
        int r = bid - 1216; trans_tile(w1, 1518, 3036, w1T, 1536, r % 96, r / 96, tid, tile);
    } else {
        int r = bid - 5824; trans_tile(w2, 3036, 3036, w2T, 3072, r % 96, r / 96, tid, tile);
    }
}

// ================= masked max pool: partials over 8 s-chunks =================
__global__ __launch_bounds__(192) void pool_k(const float* __restrict__ hs,
                                              const int* __restrict__ meta,
                                              float* __restrict__ part) {
    int b = blockIdx.x >> 3, ch = blockIdx.x & 7;
    int start = meta[b * 6 + 0], end = meta[b * 6 + 1];
    int t = threadIdx.x;
    f32x4 m = { NEGINF, NEGINF, NEGINF, NEGINF };
    const float* basep = hs + (size_t)b * 512 * 768 + t * 4;
    int s0 = ch * 64, hi = s0 + 64;
    int e1 = min(start, hi);          // keep [s0, e1)
    int s2 = max(end + 1, s0);        // keep [s2, hi)
#pragma unroll 4
    for (int s = s0; s < e1; ++s) {
        f32x4 v = *(const f32x4*)(basep + (size_t)s * 768);
#pragma unroll
        for (int j = 0; j < 4; ++j) m[j] = fmaxf(m[j], v[j]);
    }
#pragma unroll 4
    for (int s = s2; s < hi; ++s) {
        f32x4 v = *(const f32x4*)(basep + (size_t)s * 768);
#pragma unroll
        for (int j = 0; j < 4; ++j) m[j] = fmaxf(m[j], v[j]);
    }
    *(f32x4*)(part + ((size_t)b * 8 + ch) * 768 + t * 4) = m;
}

// ================= pack: reduce partials -> xA[:,0:768]; gather CITSEG row =================
__global__ __launch_bounds__(192) void pack_k(const float* __restrict__ hs,
                                              const float* __restrict__ part,
                                              const int* __restrict__ meta,
                                              unsigned short* __restrict__ xA,
                                              unsigned short* __restrict__ citA) {
    int b = blockIdx.x, t = threadIdx.x;
    const float* p = part + (size_t)b * 8 * 768 + t * 4;
    f32x4 m = *(const f32x4*)p;
#pragma unroll
    for (int ch = 1; ch < 8; ++ch) {
        f32x4 v = *(const f32x4*)(p + (size_t)ch * 768);
#pragma unroll
        for (int j = 0; j < 4; ++j) m[j] = fmaxf(m[j], v[j]);
    }
    if (!meta[b * 6 + 4]) {
        f32x4 z = {0.f, 0.f, 0.f, 0.f};
        m = z;
    }
    u16x4 o;
#pragma unroll
    for (int j = 0; j < 4; ++j) o[j] = f2b(m[j]);
    *(u16x4*)(xA + (size_t)b * 1536 + t * 4) = o;

    int cpos = meta[b * 6 + 2];
    f32x4 c = *(const f32x4*)(hs + ((size_t)b * 512 + cpos) * 768 + t * 4);
    u16x4 co;
#pragma unroll
    for (int j = 0; j < 4; ++j) co[j] = f2b(c[j]);
    *(u16x4*)(citA + (size_t)b * 768 + t * 4) = co;
}

// ================= bf16 MFMA GEMM, BK=128, dbuf LDS + global_load_lds prefetch =================
// C[M][N] = A[M][Kp] * Bt[N][Kp]^T.  EPI: 0=(+bias)*has_c  1=+bias  2=relu(+bias)
template<int EPI>
__global__ __launch_bounds__(256, 2) void gemm_k(
    const unsigned short* __restrict__ A, int lda,
    const unsigned short* __restrict__ Bt, int ldb,
    const float* __restrict__ bias, const int* __restrict__ meta,
    unsigned short* __restrict__ X, int ldx, int Nreal, int Kp) {
    __shared__ __align__(16) unsigned short As[2][64 * 128];
    __shared__ __align__(16) unsigned short Bs[2][64 * 128];
    const int tid = threadIdx.x;
    const int wid = tid >> 6, lane = tid & 63;
    const int m0 = blockIdx.y * 64, n0 = blockIdx.x * 64;
    const int wr = wid >> 1, wc = wid & 1;
    const int c_lin = lane & 15;      // 16B chunk 0..15 within 128-elem row
    const int rsub = lane >> 4;       // 0..3

    // staging source offsets (elements); swizzled source, linear LDS dest (rule #21)
    int aoff[4], boff[4], ldst[4];
#pragma unroll
    for (int i = 0; i < 4; ++i) {
        int r = wid * 16 + i * 4 + rsub;
        int csrc = (c_lin ^ (r & 15)) << 3;
        aoff[i] = (m0 + r) * lda + csrc;
        boff[i] = (n0 + r) * ldb + csrc;
        ldst[i] = (wid * 16 + i * 4) * 128;   // wave-uniform
    }
    // fragment-read offsets (elements)
    int cswz[4];
#pragma unroll
    for (int ks = 0; ks < 4; ++ks) cswz[ks] = ((ks * 4 + (lane >> 4)) ^ c_lin) << 3;
    int arow[2], brow[2];
#pragma unroll
    for (int mi = 0; mi < 2; ++mi) arow[mi] = (wr * 32 + mi * 16 + c_lin) * 128;
#pragma unroll
    for (int nj = 0; nj < 2; ++nj) brow[nj] = (wc * 32 + nj * 16 + c_lin) * 128;

    f32x4 acc[2][2];
    const f32x4 zero = {0.f, 0.f, 0.f, 0.f};
#pragma unroll
    for (int mi = 0; mi < 2; ++mi)
#pragma unroll
        for (int nj = 0; nj < 2; ++nj) acc[mi][nj] = zero;

    auto stage = [&](int nb, int kt) {
#pragma unroll
        for (int i = 0; i < 4; ++i) load_lds16(A + aoff[i] + kt, &As[nb][ldst[i]]);
#pragma unroll
        for (int i = 0; i < 4; ++i) load_lds16(Bt + boff[i] + kt, &Bs[nb][ldst[i]]);
    };

    const int nt = Kp >> 7;
    stage(0, 0);
    int cb = 0;
    for (int t = 0; t < nt; ++t) {
        __syncthreads();                    // staged tile t ready; prior reads done
        if (t + 1 < nt) stage(cb ^ 1, (t + 1) << 7);
        const unsigned short* as = As[cb];
        const unsigned short* bs = Bs[cb];
#pragma unroll
        for (int ks = 0; ks < 4; ++ks) {
            bf16x8 af[2], bfr[2];
#pragma unroll
            for (int mi = 0; mi < 2; ++mi) af[mi] = *(const bf16x8*)(as + arow[mi] + cswz[ks]);
#pragma unroll
            for (int nj = 0; nj < 2; ++nj) bfr[nj] = *(const bf16x8*)(bs + brow[nj] + cswz[ks]);
#pragma unroll
            for (int mi = 0; mi < 2; ++mi)
#pragma unroll
                for (int nj = 0; nj < 2; ++nj)
                    acc[mi][nj] = __builtin_amdgcn_mfma_f32_16x16x32_bf16(
                        af[mi], bfr[nj], acc[mi][nj], 0, 0, 0);
        }
        cb ^= 1;
    }
    // epilogue: C/D layout col=lane&15, row=(lane>>4)*4+i
#pragma unroll
    for (int mi = 0; mi < 2; ++mi) {
        int rowb = m0 + wr * 32 + mi * 16 + (lane >> 4) * 4;
#pragma unroll
        for (int nj = 0; nj < 2; ++nj) {
            int col = n0 + wc * 32 + nj * 16 + (lane & 15);
            float bv = (col < Nreal) ? bias[col] : 0.f;
#pragma unroll
            for (int i = 0; i < 4; ++i) {
                int row = rowb + i;
                float v = acc[mi][nj][i] + bv;
                if (EPI == 0) v *= (meta[row * 6 + 3] ? 1.f : 0.f);
                if (EPI == 2) v = fmaxf(v, 0.f);
                if (col >= Nreal) v = 0.f;
                X[(size_t)row * ldx + col] = f2b(v);
            }
        }
    }
}

// ================= final layer: out[b][j] = x2[b,:] . w3[:,j] + b3[j] =================
__global__ __launch_bounds__(256) void out_k(const unsigned short* __restrict__ x2,
                                             const float* __restrict__ w3,
                                             const float* __restrict__ b3,
                                             float* __restrict__ out) {
    int b = blockIdx.x, t = threadIdx.x;
    int wid = t >> 6, lane = t & 63;
    float s[6] = {0.f, 0.f, 0.f, 0.f, 0.f, 0.f};
    const unsigned short* xr = x2 + (size_t)b * 3072;
    for (int k = t; k < 3036; k += 256) {
        float x = b2f(xr[k]);
#pragma unroll
        for (int j = 0; j < 6; ++j) s[j] += x * w3[(size_t)k * 6 + j];
    }
#pragma unroll
    for (int j = 0; j < 6; ++j)
        for (int off = 1; off < 64; off <<= 1) s[j] += __shfl_xor(s[j], off);
    __shared__ float red[4][6];
    if (lane == 0) {
#pragma unroll
        for (int j = 0; j < 6; ++j) red[wid][j] = s[j];
    }
    __syncthreads();
    if (t < 6) out[b * 6 + t] = red[0][t] + red[1][t] + red[2][t] + red[3][t] + b3[t];
}

extern "C" void kernel_launch(void* const* d_in, const int* in_sizes, int n_in,
                              void* d_out, int out_size, void* d_ws, size_t ws_size,
                              hipStream_t stream) {
    const int*   tokens = (const int*)d_in[0];
    const float* hs     = (const float*)d_in[1];
    const float* proj_w = (const float*)d_in[2];
    const float* proj_b = (const float*)d_in[3];
    const float* enc_w  = (const float*)d_in[4];
    const float* enc_b  = (const float*)d_in[5];
    const float* w1 = (const float*)d_in[6];
    const float* b1 = (const float*)d_in[7];
    const float* w2 = (const float*)d_in[8];
    const float* b2 = (const float*)d_in[9];
    const float* w3 = (const float*)d_in[10];
    const float* b3 = (const float*)d_in[11];
    float* out = (float*)d_out;

    char* ws = (char*)d_ws;
    size_t off = 0;
    auto alloc = [&](size_t bytes) {
        void* p = ws + off;
        off = (off + bytes + 255) & ~(size_t)255;
        return p;
    };
    int* meta            = (int*)alloc(256 * 6 * sizeof(int));
    float* part          = (float*)alloc((size_t)256 * 8 * 768 * sizeof(float));
    unsigned short* xA   = (unsigned short*)alloc((size_t)256 * 1536 * 2);
    unsigned short* citA = (unsigned short*)alloc((size_t)256 * 768 * 2);
    unsigned short* citB = (unsigned short*)alloc((size_t)256 * 768 * 2);
    unsigned short* x1   = (unsigned short*)alloc((size_t)256 * 3072 * 2);
    unsigned short* x2   = (unsigned short*)alloc((size_t)256 * 3072 * 2);
    unsigned short* projT= (unsigned short*)alloc((size_t)768 * 768 * 2);
    unsigned short* encT = (unsigned short*)alloc((size_t)768 * 768 * 2);
    unsigned short* w1T  = (unsigned short*)alloc((size_t)3072 * 1536 * 2);
    unsigned short* w2T  = (unsigned short*)alloc((size_t)3072 * 3072 * 2);

    // prep: scan (64) + transposes of proj/enc/w1/w2 (w3 consumed as f32 directly)
    prep_k<<<15040, 256, 0, stream>>>(tokens, meta, proj_w, enc_w, w1, w2,
                                      projT, encT, w1T, w2T);
    pool_k<<<2048, 192, 0, stream>>>(hs, meta, part);
    pack_k<<<256, 192, 0, stream>>>(hs, part, meta, xA, citA);

    // G1: cit = (cit_h @ proj_w + proj_b) * has_c     [256x768]x[768x750]
    gemm_k<0><<<dim3(12, 4), 256, 0, stream>>>(citA, 768, projT, 768, proj_b, meta,
                                               citB, 768, 750, 768);
    // G2: cit_enc = cit @ enc_w + enc_b -> xA[:,768:1518]
    gemm_k<1><<<dim3(12, 4), 256, 0, stream>>>(citB, 768, encT, 768, enc_b, meta,
                                               xA + 768, 1536, 750, 768);
    // G3: x1 = relu(xA @ w1 + b1)                      [256x1536]x[1536x3072]
    gemm_k<2><<<dim3(48, 4), 256, 0, stream>>>(xA, 1536, w1T, 1536, b1, meta,
                                               x1, 3072, 3036, 1536);
    // G4: x2 = relu(x1 @ w2 + b2)                      [256x3072]x[3072x3072]
    gemm_k<2><<<dim3(48, 4), 256, 0, stream>>>(x1, 3072, w2T, 3072, b2, meta,
                                               x2, 3072, 3036, 3072);
    // G5
    out_k<<<256, 256, 0, stream>>>(x2, w3, b3, out);
}